// Round 11
// baseline (186.612 us; speedup 1.0000x reference)
//
#include <hip/hip_runtime.h>
#include <math.h>

// Problem constants: B=16, C=256, H=W=64, N=4096, GROUPS=16 (cg=16), HEADS=8 (ch=32)

__device__ __forceinline__ float sigmoidf_(float v) { return 1.0f / (1.0f + __expf(-v)); }

typedef _Float16 half8 __attribute__((ext_vector_type(8)));
typedef _Float16 half4 __attribute__((ext_vector_type(4)));
typedef float f32x4 __attribute__((ext_vector_type(4)));

#define GLOAD_LDS16(gp, lp)                                                     \
    __builtin_amdgcn_global_load_lds(                                           \
        (const __attribute__((address_space(1))) void*)(gp),                    \
        (__attribute__((address_space(3))) void*)(lp), 16, 0, 0)

// ---------------------------------------------------------------------------
// prep_fused: X (fp32 [b][256][4096]) -> Xh (f16 row-major) + Xt (f16 [b][4096][256])
// ---------------------------------------------------------------------------
__global__ __launch_bounds__(256) void prep_fused(
    const float* __restrict__ X, _Float16* __restrict__ Xh, _Float16* __restrict__ Xt)
{
    __shared__ float tl[64][68];
    const int b = blockIdx.z, c0 = blockIdx.y * 64, n0 = blockIdx.x * 64;
    const int t = threadIdx.x;
    const int r0 = t >> 4;
    const int q = (t & 15) * 4;
    const float* Xb = X + ((long)b * 256 + c0) * 4096 + n0;
    _Float16* Xhb = Xh + ((long)b * 256 + c0) * 4096 + n0;
    #pragma unroll
    for (int i = 0; i < 4; ++i) {
        const int r = r0 + i * 16;
        const float4 v = *(const float4*)(Xb + (long)r * 4096 + q);
        tl[r][q + 0] = v.x; tl[r][q + 1] = v.y;
        tl[r][q + 2] = v.z; tl[r][q + 3] = v.w;
        half4 h = { (_Float16)v.x, (_Float16)v.y, (_Float16)v.z, (_Float16)v.w };
        *(half4*)(Xhb + (long)r * 4096 + q) = h;
    }
    __syncthreads();
    const int nn = t >> 2, cc = (t & 3) * 16;
    _Float16* Xtb = Xt + ((long)b * 4096 + n0 + nn) * 256 + c0 + cc;
    half8 o0, o1;
    #pragma unroll
    for (int k = 0; k < 8; ++k) o0[k] = (_Float16)tl[cc + k][nn];
    #pragma unroll
    for (int k = 0; k < 8; ++k) o1[k] = (_Float16)tl[cc + 8 + k][nn];
    *(half8*)(Xtb) = o0;
    *(half8*)(Xtb + 8) = o1;
}

// ---------------------------------------------------------------------------
// Gram split-K: pG[s][b] = Xh_b[:, s*512:(s+1)*512] . (same)^T
// pG lives in d_out (dead until out_fused overwrites). Slab stride 1048576 fl.
// ---------------------------------------------------------------------------
__global__ __launch_bounds__(256) void gram_split(const _Float16* __restrict__ Xh,
                                                  float* __restrict__ pG)
{
    __shared__ _Float16 Al[128 * 32];
    __shared__ _Float16 Bl[128 * 32];
    const int z = blockIdx.z, b = z >> 3, s = z & 7;
    const int m0 = blockIdx.y * 128, n0 = blockIdx.x * 128;
    const _Float16* Xb = Xh + (long)b * 256 * 4096;
    const int t = threadIdx.x, lane = t & 63, wv = t >> 6;
    const int wm = (wv >> 1) * 64, wn = (wv & 1) * 64;
    f32x4 acc[4][4] = {};

    const int kbeg = s * 512, kend = kbeg + 512;
    for (int k0 = kbeg; k0 < kend; k0 += 32) {
        __syncthreads();
        #pragma unroll
        for (int r = 0; r < 2; ++r) {
            const int e = (r * 256 + t) * 8;
            const int row = e >> 5, col = e & 31;
            GLOAD_LDS16(Xb + (long)(m0 + row) * 4096 + k0 + col, &Al[e]);
            GLOAD_LDS16(Xb + (long)(n0 + row) * 4096 + k0 + col, &Bl[e]);
        }
        __syncthreads();
        half8 af[4], bf[4];
        #pragma unroll
        for (int f = 0; f < 4; ++f) {
            af[f] = *(const half8*)&Al[(wm + f * 16 + (lane & 15)) * 32 + (lane >> 4) * 8];
            bf[f] = *(const half8*)&Bl[(wn + f * 16 + (lane & 15)) * 32 + (lane >> 4) * 8];
        }
        #pragma unroll
        for (int i = 0; i < 4; ++i)
            #pragma unroll
            for (int j = 0; j < 4; ++j)
                acc[i][j] = __builtin_amdgcn_mfma_f32_16x16x32_f16(af[i], bf[j], acc[i][j], 0, 0, 0);
    }
    float* pGb = pG + (long)s * 1048576 + (long)b * 65536;
    #pragma unroll
    for (int i = 0; i < 4; ++i)
        #pragma unroll
        for (int j = 0; j < 4; ++j) {
            const int row = m0 + wm + i * 16 + (lane >> 4) * 4;
            const int col = n0 + wn + j * 16 + (lane & 15);
            float* gp = pGb + (long)row * 256 + col;
            #pragma unroll
            for (int r = 0; r < 4; ++r) gp[(long)r * 256] = acc[i][j][r];
        }
}

// ---------------------------------------------------------------------------
// G = sum_s pG[s]  (fixed order -> deterministic)
// ---------------------------------------------------------------------------
__global__ __launch_bounds__(256) void reduce_g(const float* __restrict__ pG,
                                                float* __restrict__ G)
{
    const long i = ((long)blockIdx.x * 256 + threadIdx.x) * 4;
    f32x4 s = {};
    #pragma unroll
    for (int k = 0; k < 8; ++k) {
        const float4 v = *(const float4*)(pG + (long)k * 1048576 + i);
        s[0] += v.x; s[1] += v.y; s[2] += v.z; s[3] += v.w;
    }
    *(f32x4*)(G + i) = s;
}

// ---------------------------------------------------------------------------
// snorm: Qn[b][r] = T[b][r] . wqkv[r]  for r in [0,512)  (q/k norms^2).
// ---------------------------------------------------------------------------
__global__ __launch_bounds__(256) void snorm_kernel(
    const float* __restrict__ T, const float* __restrict__ wqkv,
    float* __restrict__ Qn)
{
    const int gw = (int)((blockIdx.x * 256 + threadIdx.x) >> 6);
    const int lane = threadIdx.x & 63;
    const int b = gw >> 9, r = gw & 511;
    const float4 a = *(const float4*)(T + (long)b * 131072 + (long)r * 256 + lane * 4);
    const float4 w = *(const float4*)(wqkv + (long)r * 256 + lane * 4);
    float s = a.x * w.x + a.y * w.y + a.z * w.z + a.w * w.w;
    #pragma unroll
    for (int off = 32; off; off >>= 1) s += __shfl_xor(s, off, 64);
    if (lane == 0) Qn[(long)b * 512 + r] = s;
}

// ---------------------------------------------------------------------------
// attn2: per (b,h): softmax(S1 head-block / (qn kn) * temp) @ Wv_h -> M rows.
// S1 and Mout alias (tile staged to LDS first; blocks touch disjoint rows).
// ---------------------------------------------------------------------------
__global__ __launch_bounds__(256) void attn2_kernel(
    const float* __restrict__ S1, const float* __restrict__ Qn,
    const float* __restrict__ wqkv, const float* __restrict__ temp,
    float* __restrict__ Mout)
{
    const int bh = blockIdx.x;
    const int b = bh >> 3, h = bh & 7;
    const int t = threadIdx.x;
    __shared__ float pa[32][36];
    __shared__ float qn[32], kn[32];

    {
        const int r = t >> 3, c4 = (t & 7) * 4;
        const float4 v = *(const float4*)(
            S1 + (long)b * 65536 + (long)(h * 32 + r) * 256 + h * 32 + c4);
        pa[r][c4 + 0] = v.x; pa[r][c4 + 1] = v.y;
        pa[r][c4 + 2] = v.z; pa[r][c4 + 3] = v.w;
    }
    if (t < 32)
        qn[t] = fmaxf(sqrtf(Qn[(long)b * 512 + h * 32 + t]), 1e-12f);
    else if (t < 64)
        kn[t - 32] = fmaxf(sqrtf(Qn[(long)b * 512 + 256 + h * 32 + (t - 32)]), 1e-12f);
    __syncthreads();

    if (t < 32) {
        const float qin = temp[h] / qn[t];
        float lg[32];
        float mx = -1e30f;
        #pragma unroll
        for (int d = 0; d < 32; ++d) {
            const float l = pa[t][d] * qin / kn[d];
            lg[d] = l;
            mx = fmaxf(mx, l);
        }
        float s = 0.f;
        #pragma unroll
        for (int d = 0; d < 32; ++d) { lg[d] = __expf(lg[d] - mx); s += lg[d]; }
        const float inv = 1.0f / s;
        #pragma unroll
        for (int d = 0; d < 32; ++d) pa[t][d] = lg[d] * inv;
    }
    __syncthreads();

    float accm[32];
    #pragma unroll
    for (int c = 0; c < 32; ++c) accm[c] = 0.f;
    const float* wvp = wqkv + (long)(512 + h * 32) * 256 + t;
    #pragma unroll 4
    for (int d = 0; d < 32; ++d) {
        const float wvv = wvp[(long)d * 256];
        #pragma unroll
        for (int c = 0; c < 32; ++c) accm[c] += pa[c][d] * wvv;
    }
    float* mo = Mout + (long)b * 65536 + (long)(h * 32) * 256 + t;
    #pragma unroll
    for (int c = 0; c < 32; ++c) mo[(long)c * 256] = accm[c];
}

// ---------------------------------------------------------------------------
// wpre_h: WP[b][g][n] = W2_b[g] . Xh_b[:,n]  (f16 input halves traffic)
// ---------------------------------------------------------------------------
__global__ __launch_bounds__(256) void wpre_h(
    const float* __restrict__ W2, const _Float16* __restrict__ Xh,
    float* __restrict__ WP)
{
    __shared__ float w2s[16][260];
    const int b = blockIdx.y;
    const int n = blockIdx.x * 256 + threadIdx.x;
    for (int f = threadIdx.x; f < 16 * 64; f += 256) {
        const int g = f >> 6, c4 = f & 63;
        *(float4*)&w2s[g][c4 * 4] = *(const float4*)(W2 + ((long)b * 16 + g) * 256 + c4 * 4);
    }
    __syncthreads();
    float acc[16] = {};
    const _Float16* xb = Xh + (long)b * 1048576 + n;
    for (int k = 0; k < 256; ++k) {
        const float xv = (float)xb[(long)k * 4096];
        #pragma unroll
        for (int g = 0; g < 16; ++g) acc[g] += w2s[g][k] * xv;
    }
    #pragma unroll
    for (int g = 0; g < 16; ++g) WP[((long)b * 16 + g) * 4096 + n] = acc[g];
}

// ---------------------------------------------------------------------------
// out_fused: out_b = Ph_b @ X_b (via Xt) + Xh*sigmoid(WP).
// Counted-vmcnt 2-buffer pipeline (T4). RACE FIX vs R10: the two prologue
// stages MUST be fenced apart — global_load_lds intrinsics to disjoint
// addresses are reorderable, so without a fence the scheduler can interleave
// S0/S1 loads and vmcnt(4) no longer means "S0 landed". Every waitcnt/barrier
// also gets sched_barrier(0) (rule #18). K-loop has ZERO other vmem ops
// (gate/Xh reads are in the epilogue), so the count is exact.
// LDS = 32768 B exactly (2x16K bufs; epilogue reuses as cst[64][128])
// -> 5 blocks/CU. VGPR ~84 (no S2 fusion).
// ---------------------------------------------------------------------------
__global__ __launch_bounds__(256) void out_fused(
    const _Float16* __restrict__ Ph, const _Float16* __restrict__ Xt,
    const _Float16* __restrict__ Xh, const float* __restrict__ WP,
    float* __restrict__ out)
{
    __shared__ __align__(16) char smem[32768];   // [buf0 16K][buf1 16K]
    float (*cst)[128] = (float(*)[128])smem;     // epilogue overlay, 32768 B

    const int b = blockIdx.z;
    const int m0 = blockIdx.y * 128, n0 = blockIdx.x * 128;
    const _Float16* Ab = Ph + (long)b * 65536;
    const _Float16* Bb = Xt + (long)b * 1048576;
    const int t = threadIdx.x, lane = t & 63, wv = t >> 6;
    const int wm = (wv >> 1) * 64, wn = (wv & 1) * 64;

    f32x4 acc[4][4] = {};

#define OF_STAGE(P, K0) do {                                                     \
        _Float16* Al_ = (_Float16*)(smem + (P) * 16384);                         \
        _Float16* Bl_ = (_Float16*)(smem + (P) * 16384 + 8192);                  \
        _Pragma("unroll")                                                        \
        for (int r_ = 0; r_ < 2; ++r_) {                                         \
            const int e_ = (r_ * 256 + t) * 8;                                   \
            const int row_ = e_ >> 5, col_ = e_ & 31;                            \
            GLOAD_LDS16(Ab + (long)(m0 + row_) * 256 + (K0) + col_, &Al_[e_]);   \
            GLOAD_LDS16(Bb + (long)(n0 + row_) * 256 + (K0) + col_, &Bl_[e_]);   \
        } } while (0)

#define OF_FENCE() do { asm volatile("" ::: "memory");                           \
        __builtin_amdgcn_sched_barrier(0); } while (0)

    OF_STAGE(0, 0);
    OF_FENCE();                          // pin S0's 4 loads before S1's
    OF_STAGE(1, 32);
    OF_FENCE();

    int cur = 0;
    for (int ks = 0; ks < 8; ++ks) {
        if (ks < 7) asm volatile("s_waitcnt vmcnt(4)" ::: "memory");
        else        asm volatile("s_waitcnt vmcnt(0)" ::: "memory");
        __builtin_amdgcn_sched_barrier(0);
        __builtin_amdgcn_s_barrier();    // all waves: buf[cur] fully staged
        __builtin_amdgcn_sched_barrier(0);

        const _Float16* Al = (const _Float16*)(smem + cur * 16384);
        const _Float16* Bl = (const _Float16*)(smem + cur * 16384 + 8192);
        half8 af[4], bf[4];
        #pragma unroll
        for (int f = 0; f < 4; ++f) {
            af[f] = *(const half8*)&Al[(wm + f * 16 + (lane & 15)) * 32 + (lane >> 4) * 8];
            bf[f] = *(const half8*)&Bl[(wn + f * 16 + (lane & 15)) * 32 + (lane >> 4) * 8];
        }
        #pragma unroll
        for (int i = 0; i < 4; ++i)
            #pragma unroll
            for (int j = 0; j < 4; ++j)
                acc[i][j] = __builtin_amdgcn_mfma_f32_16x16x32_f16(af[i], bf[j], acc[i][j], 0, 0, 0);

        OF_FENCE();
        __builtin_amdgcn_s_barrier();    // all waves done reading buf[cur]
        __builtin_amdgcn_sched_barrier(0);
        if (ks < 6) OF_STAGE(cur, (ks + 2) * 32);   // refill freed buffer
        OF_FENCE();
        cur ^= 1;
    }
#undef OF_STAGE
#undef OF_FENCE

    // --- epilogue (R7-proven shape): block-wide cst staging, coalesced ---
    const float* WPb = WP + (long)b * 65536;
    const _Float16* Xhb = Xh + (long)b * 1048576;
    float* ob = out + (long)b * 1048576;

    #pragma unroll
    for (int hf = 0; hf < 2; ++hf) {
        if (wm == hf * 64) {
            #pragma unroll
            for (int i = 0; i < 4; ++i)
                #pragma unroll
                for (int j = 0; j < 4; ++j)
                    #pragma unroll
                    for (int r = 0; r < 4; ++r)
                        cst[i * 16 + (lane >> 4) * 4 + r][wn + j * 16 + (lane & 15)] = acc[i][j][r];
        }
        __syncthreads();
        #pragma unroll
        for (int it = 0; it < 8; ++it) {
            const int row = it * 8 + (t >> 5);
            const int col = (t & 31) * 4;
            const int c = m0 + hf * 64 + row;
            const float4 v = *(const float4*)&cst[row][col];
            const float4 s2 = *(const float4*)(WPb + (long)(c >> 4) * 4096 + n0 + col);
            const half4 xv = *(const half4*)(Xhb + (long)c * 4096 + n0 + col);
            float4 o;
            o.x = (float)xv[0] * sigmoidf_(s2.x) + v.x;
            o.y = (float)xv[1] * sigmoidf_(s2.y) + v.y;
            o.z = (float)xv[2] * sigmoidf_(s2.z) + v.z;
            o.w = (float)xv[3] * sigmoidf_(s2.w) + v.w;
            *(float4*)(ob + (long)c * 4096 + n0 + col) = o;
        }
        __syncthreads();
    }
}

// ---------------------------------------------------------------------------
// Generic 64x64-tile fp32 GEMM. DIAG: n0=m0 (block-diagonal tiles only).
// HC: also write an f16 copy of C (same layout).
// ---------------------------------------------------------------------------
template <bool BT, bool EPI, bool DIAG, bool HC>
__global__ __launch_bounds__(256) void gemm64(
    const float* __restrict__ A, const float* __restrict__ B, float* __restrict__ C,
    int M, int N, int K, long sA, long sB, long sC,
    const float* __restrict__ X, const float* __restrict__ WP,
    _Float16* __restrict__ Hc)
{
    __shared__ float As[32][68];
    __shared__ float Bs[32][68];
    const int b = blockIdx.z;
    const float* Ab = A + (long)b * sA;
    const float* Bb = B + (long)b * sB;
    float* Cb = C + (long)b * sC;
    const int t = threadIdx.x;
    const int tx = t & 15, ty = t >> 4;
    const int m0 = blockIdx.y * 64;
    const int n0 = DIAG ? m0 : blockIdx.x * 64;

    float acc[4][4] = {};

    for (int k0 = 0; k0 < K; k0 += 32) {
        __syncthreads();
        #pragma unroll
        for (int f0 = 0; f0 < 512; f0 += 256) {
            const int f = f0 + t;
            const int row = f >> 3, c4 = f & 7;
            const float4 v = *(const float4*)(Ab + (long)(m0 + row) * K + k0 + c4 * 4);
            As[c4 * 4 + 0][row] = v.x;
            As[c4 * 4 + 1][row] = v.y;
            As[c4 * 4 + 2][row] = v.z;
            As[c4 * 4 + 3][row] = v.w;
        }
        if (BT) {
            #pragma unroll
            for (int f0 = 0; f0 < 512; f0 += 256) {
                const int f = f0 + t;
                const int row = f >> 3, c4 = f & 7;
                const float4 v = *(const float4*)(Bb + (long)(n0 + row) * K + k0 + c4 * 4);
                Bs[c4 * 4 + 0][row] = v.x;
                Bs[c4 * 4 + 1][row] = v.y;
                Bs[c4 * 4 + 2][row] = v.z;
                Bs[c4 * 4 + 3][row] = v.w;
            }
        } else {
            #pragma unroll
            for (int f0 = 0; f0 < 512; f0 += 256) {
                const int f = f0 + t;
                const int kk = f >> 4, c4 = f & 15;
                *(float4*)&Bs[kk][c4 * 4] =
                    *(const float4*)(Bb + (long)(k0 + kk) * N + n0 + c4 * 4);
            }
        }
        __syncthreads();
        #pragma unroll
        for (int kk = 0; kk < 32; ++kk) {
            const float4 av = *(const float4*)&As[kk][ty * 4];
            const float4 bv = *(const float4*)&Bs[kk][tx * 4];
            const float a0 = av.x, a1 = av.y, a2 = av.z, a3 = av.w;
            const float b0 = bv.x, b1 = bv.y, b2 = bv.z, b3 = bv.w;
            acc[0][0] += a0 * b0; acc[0][1] += a0 * b1; acc[0][2] += a0 * b2; acc[0][3] += a0 * b3;
            acc[1][0] += a1 * b0; acc[1][1] += a1 * b1; acc[1][2] += a1 * b2; acc[1][3] += a1 * b3;
            acc[2][0] += a2 * b0; acc[2][1] += a2 * b1; acc[2][2] += a2 * b2; acc[2][3] += a2 * b3;
            acc[3][0] += a3 * b0; acc[3][1] += a3 * b1; acc[3][2] += a3 * b2; acc[3][3] += a3 * b3;
        }
    }

    if (EPI) {
        #pragma unroll
        for (int i = 0; i < 4; ++i) {
            const int c = m0 + ty * 4 + i;
            const long nidx = n0 + tx * 4;
            const float4 xv = *(const float4*)(X + ((long)b * 256 + c) * 4096 + nidx);
            const float4 wv = *(const float4*)(WP + ((long)b * 16 + (c >> 4)) * 4096 + nidx);
            float4 o;
            o.x = xv.x * sigmoidf_(wv.x) + acc[i][0];
            o.y = xv.y * sigmoidf_(wv.y) + acc[i][1];
            o.z = xv.z * sigmoidf_(wv.z) + acc[i][2];
            o.w = xv.w * sigmoidf_(wv.w) + acc[i][3];
            *(float4*)(Cb + (long)c * N + nidx) = o;
        }
    } else {
        #pragma unroll
        for (int i = 0; i < 4; ++i) {
            const float4 o = make_float4(acc[i][0], acc[i][1], acc[i][2], acc[i][3]);
            *(float4*)(Cb + (long)(m0 + ty * 4 + i) * N + n0 + tx * 4) = o;
            if (HC) {
                half4 h = { (_Float16)o.x, (_Float16)o.y, (_Float16)o.z, (_Float16)o.w };
                *(half4*)(Hc + (long)b * sC + (long)(m0 + ty * 4 + i) * N + n0 + tx * 4) = h;
            }
        }
    }
}

// ---------------------------------------------------------------------------
// Per-(b,h) attention in Gram space (fallback path only).
// ---------------------------------------------------------------------------
__global__ __launch_bounds__(256) void attn_kernel(
    const float* __restrict__ T, const float* __restrict__ wqkv,
    const float* __restrict__ temp, float* __restrict__ Mout, long tStride)
{
    const int bh = blockIdx.x;
    const int b = bh >> 3, h = bh & 7;
    const int t = threadIdx.x;
    __shared__ float Tq[32][260];
    __shared__ float qk[32][33];
    __shared__ float qn[32], kn[32];
    const float* Tb = T + (long)b * tStride;

    for (int f = t; f < 32 * 64; f += 256) {
        const int r = f >> 6, c4 = f & 63;
        *(float4*)&Tq[r][c4 * 4] = *(const float4*)(Tb + (long)(h * 32 + r) * 256 + c4 * 4);
    }
    __syncthreads();

    if (t < 32) {
        float s = 0.f;
        const float* wq = wqkv + (long)(h * 32 + t) * 256;
        #pragma unroll 4
        for (int k = 0; k < 256; k += 4) {
            const float4 a = *(const float4*)&Tq[t][k];
            const float4 w = *(const float4*)(wq + k);
            s += a.x * w.x + a.y * w.y + a.z * w.z + a.w * w.w;
        }
        qn[t] = fmaxf(sqrtf(s), 1e-12f);
    } else if (t < 64) {
        const int d = t - 32;
        float s = 0.f;
        const float* tk = Tb + (long)(256 + h * 32 + d) * 256;
        const float* wk = wqkv + (long)(256 + h * 32 + d) * 256;
        #pragma unroll 4
        for (int k = 0; k < 256; k += 4) {
            const float4 a = *(const float4*)(tk + k);
            const float4 w = *(const float4*)(wk + k);
            s += a.x * w.x + a.y * w.y + a.z * w.z + a.w * w.w;
        }
        kn[d] = fmaxf(sqrtf(s), 1e-12f);
    }

    {
        const int c = t >> 3, d0 = (t & 7) * 4;
        float s0 = 0, s1 = 0, s2 = 0, s3 = 0;
        const float* wk0 = wqkv + (long)(256 + h * 32 + d0) * 256;
        #pragma unroll 4
        for (int k = 0; k < 256; k += 4) {
            const float4 a = *(const float4*)&Tq[c][k];
            const float4 w0 = *(const float4*)(wk0 + k);
            const float4 w1 = *(const float4*)(wk0 + 256 + k);
            const float4 w2 = *(const float4*)(wk0 + 512 + k);
            const float4 w3 = *(const float4*)(wk0 + 768 + k);
            s0 += a.x * w0.x + a.y * w0.y + a.z * w0.z + a.w * w0.w;
            s1 += a.x * w1.x + a.y * w1.y + a.z * w1.z + a.w * w1.w;
            s2 += a.x * w2.x + a.y * w2.y + a.z * w2.z + a.w * w2.w;
            s3 += a.x * w3.x + a.y * w3.y + a.z * w3.z + a.w * w3.w;
        }
        qk[c][d0 + 0] = s0;
        qk[c][d0 + 1] = s1;
        qk[c][d0 + 2] = s2;
        qk[c][d0 + 3] = s3;
    }
    __syncthreads();

    if (t < 32) {
        const float tscale = temp[h];
        const float qin = tscale / qn[t];
        float lg[32];
        float mx = -1e30f;
        #pragma unroll
        for (int d = 0; d < 32; ++d) {
            const float l = qk[t][d] * qin / kn[d];
            lg[d] = l;
            mx = fmaxf(mx, l);
        }
        float s = 0.f;
        #pragma unroll
        for (int d = 0; d < 32; ++d) { lg[d] = __expf(lg[d] - mx); s += lg[d]; }
        const float inv = 1.0f / s;
        #pragma unroll
        for (int d = 0; d < 32; ++d) qk[t][d] = lg[d] * inv;
    }
    __syncthreads();

    float accm[32];
    #pragma unroll
    for (int c = 0; c < 32; ++c) accm[c] = 0.f;
    const float* wvp = wqkv + (long)(512 + h * 32) * 256 + t;
    #pragma unroll 4
    for (int d = 0; d < 32; ++d) {
        const float wvv = wvp[(long)d * 256];
        #pragma unroll
        for (int c = 0; c < 32; ++c) accm[c] += qk[c][d] * wvv;
    }
    float* mo = Mout + (long)b * 256 * 256 + (long)(h * 32) * 256 + t;
    #pragma unroll
    for (int c = 0; c < 32; ++c) mo[(long)c * 256] = accm[c];
}

// ---------------------------------------------------------------------------
// W2[b][g][i] = (softmax(gn_b) . P[b][16g:16g+16][i])
// ---------------------------------------------------------------------------
template <typename OT>
__global__ __launch_bounds__(256) void w2_kernel(
    const float* __restrict__ P, const float* __restrict__ gnb, OT* __restrict__ W2)
{
    const int b = blockIdx.x, i = threadIdx.x;
    float e[16];
    float mx = -1e30f;
    #pragma unroll
    for (int c = 0; c < 16; ++c) mx = fmaxf(mx, gnb[c]);
    float s = 0.f;
    #pragma unroll
    for (int c = 0; c < 16; ++c) { e[c] = __expf(gnb[c] - mx); s += e[c]; }
    const float inv = 1.0f / s;
    const float* Pb = P + (long)b * 256 * 256 + i;
    #pragma unroll
    for (int g = 0; g < 16; ++g) {
        float acc = 0.f;
        #pragma unroll
        for (int c = 0; c < 16; ++c) acc += e[c] * Pb[(long)(g * 16 + c) * 256];
        W2[((long)b * 16 + g) * 256 + i] = (OT)(acc * inv);
    }
}

// ---------------------------------------------------------------------------
// WP[b][g][n] = W2_b[g] . X_b[:,n]  (fallback path, fp32 X)
// ---------------------------------------------------------------------------
__global__ __launch_bounds__(256) void wpre_kernel(
    const float* __restrict__ W2, const float* __restrict__ X, float* __restrict__ WP)
{
    __shared__ float w2s[16][260];
    const int b = blockIdx.y;
    const int n = blockIdx.x * 256 + threadIdx.x;
    for (int f = threadIdx.x; f < 16 * 64; f += 256) {
        const int g = f >> 6, c4 = f & 63;
        *(float4*)&w2s[g][c4 * 4] = *(const float4*)(W2 + ((long)b * 16 + g) * 256 + c4 * 4);
    }
    __syncthreads();
    float acc[16] = {};
    const float* xb = X + (long)b * 256 * 4096 + n;
    for (int k = 0; k < 256; ++k) {
        const float xv = xb[(long)k * 4096];
        #pragma unroll
        for (int g = 0; g < 16; ++g) acc[g] += w2s[g][k] * xv;
    }
    #pragma unroll
    for (int g = 0; g < 16; ++g) WP[((long)b * 16 + g) * 4096 + n] = acc[g];
}

// ---------------------------------------------------------------------------
extern "C" void kernel_launch(void* const* d_in, const int* in_sizes, int n_in,
                              void* d_out, int out_size, void* d_ws, size_t ws_size,
                              hipStream_t stream)
{
    const float* x     = (const float*)d_in[0];
    const float* gnb   = (const float*)d_in[4];
    const float* wqkv  = (const float*)d_in[5];
    const float* wproj = (const float*)d_in[6];
    const float* temp  = (const float*)d_in[7];
    float* out = (float*)d_out;

    if (ws_size >= 82051072ULL) {
        // Workspace: [Xh 32M][Xt 32M][G/S1/Mm 4M]
        // [pool 10.25M: {T 8M, Qn 32K} -> {P 4M, Ph 2M, W2f 256K, WP 4M}]
        // Gram split-K partials (32 MB) live in d_out (dead until out_fused).
        char* w = (char*)d_ws;
        _Float16* Xh = (_Float16*)w;
        _Float16* Xt = (_Float16*)(w + 33554432);
        float*    G  = (float*)(w + 67108864);
        float*    S1 = G;                           // overlay: G dead after T-gemm
        float*    Mm = G;                           // overlay: attn2 stages S1 in LDS
        char*     pool = w + 71303168;
        float*    T   = (float*)pool;               // 8MB, dead after snorm/S1
        float*    Qn  = (float*)(pool + 8388608);   // 32KB, dead after attn2
        float*    P   = (float*)pool;               // 4MB, overwrites dead T
        _Float16* Ph  = (_Float16*)(pool + 4194304);// 2MB
        float*    W2f = (float*)(pool + 6291456);   // 256KB
        float*    WP  = (float*)(pool + 6553600);   // 4MB (overlaps dead Qn - ok)
        float*    pG  = (float*)d_out;              // scratch, overwritten later

        // 1. X -> Xh + Xt (one pass)
        prep_fused<<<dim3(64, 4, 16), 256, 0, stream>>>(x, Xh, Xt);
        // 2. Gram split-K partials into d_out
        gram_split<<<dim3(2, 2, 128), 256, 0, stream>>>(Xh, pG);
        // 3. G = sum of 8 partials (fixed order)
        reduce_g<<<1024, 256, 0, stream>>>(pG, G);
        // 4. T = wqkv[0:512] @ G_b
        gemm64<false, false, false, false><<<dim3(4, 8, 16), 256, 0, stream>>>(
            wqkv, G, T, 512, 256, 256, 0L, 65536L, 131072L,
            nullptr, nullptr, nullptr);
        // 5. Qn[b][r] = T[b][r].wqkv[r]
        snorm_kernel<<<2048, 256, 0, stream>>>(T, wqkv, Qn);
        // 6. S1 diag head-blocks = Tq @ Wk^T (overlays dead G)
        gemm64<true, false, true, false><<<dim3(1, 4, 16), 256, 0, stream>>>(
            T, wqkv + 65536, S1, 256, 256, 256, 131072L, 0L, 65536L,
            nullptr, nullptr, nullptr);
        // 7. softmax + @Wv -> Mm (aliases S1, LDS-staged)
        attn2_kernel<<<128, 256, 0, stream>>>(S1, Qn, wqkv, temp, Mm);
        // 8. P = wproj @ Mm (fp32) + f16 copy Ph (fused cvt)
        gemm64<false, false, false, true><<<dim3(4, 4, 16), 256, 0, stream>>>(
            wproj, Mm, P, 256, 256, 256, 0L, 65536L, 65536L,
            nullptr, nullptr, Ph);
        // 9. W2f = softmax(gn_b)-weighted group sums of P rows (fp32)
        w2_kernel<float><<<16, 256, 0, stream>>>(P, gnb, W2f);
        // 10. WP = W2_b @ Xh_b (gate pre-activation)
        wpre_h<<<dim3(16, 16), 256, 0, stream>>>(W2f, Xh, WP);
        // 11. out = Ph@X + Xh*sigmoid(WP)  (fenced counted-vmcnt pipeline)
        out_fused<<<dim3(32, 2, 16), 256, 0, stream>>>(Ph, Xt, Xh, WP, out);
    } else {
        // Fallback: fp32 path (~30 MB workspace)
        float* ws = (float*)d_ws;
        float* G  = ws;
        float* T  = G  + 16L * 65536;
        float* Mm = T  + 16L * 196608;
        float* P  = Mm + 16L * 65536;
        float* W2 = P  + 16L * 65536;
        float* WP = W2 + 16L * 4096;

        gemm64<true, false, false, false><<<dim3(4, 4, 16), 256, 0, stream>>>(
            x, x, G, 256, 256, 4096, 1048576L, 1048576L, 65536L, nullptr, nullptr, nullptr);
        gemm64<false, false, false, false><<<dim3(4, 12, 16), 256, 0, stream>>>(
            wqkv, G, T, 768, 256, 256, 0L, 65536L, 196608L, nullptr, nullptr, nullptr);
        attn_kernel<<<128, 256, 0, stream>>>(T, wqkv, temp, Mm, 196608L);
        gemm64<false, false, false, false><<<dim3(4, 4, 16), 256, 0, stream>>>(
            wproj, Mm, P, 256, 256, 256, 0L, 65536L, 65536L, nullptr, nullptr, nullptr);
        w2_kernel<float><<<16, 256, 0, stream>>>(P, gnb, W2);
        wpre_kernel<<<dim3(16, 16), 256, 0, stream>>>(W2, x, WP);
        gemm64<false, true, false, false><<<dim3(64, 4, 16), 256, 0, stream>>>(
            P, x, out, 256, 4096, 256, 65536L, 1048576L, 1048576L, x, WP, nullptr);
    }
}

// Round 12
// 150.514 us; speedup vs baseline: 1.2398x; 1.2398x over previous
//
#include <hip/hip_runtime.h>
#include <math.h>

// Problem constants: B=16, C=256, H=W=64, N=4096, GROUPS=16 (cg=16), HEADS=8 (ch=32)

__device__ __forceinline__ float sigmoidf_(float v) { return 1.0f / (1.0f + __expf(-v)); }

typedef _Float16 half8 __attribute__((ext_vector_type(8)));
typedef _Float16 half4 __attribute__((ext_vector_type(4)));
typedef float f32x4 __attribute__((ext_vector_type(4)));

#define GLOAD_LDS16(gp, lp)                                                     \
    __builtin_amdgcn_global_load_lds(                                           \
        (const __attribute__((address_space(1))) void*)(gp),                    \
        (__attribute__((address_space(3))) void*)(lp), 16, 0, 0)

// ---------------------------------------------------------------------------
// prep_fused: X (fp32 [b][256][4096]) -> Xh (f16 row-major) + Xt (f16 [b][4096][256])
// Pure streaming, no inter-block reuse -> no swizzle (T1 null here).
// ---------------------------------------------------------------------------
__global__ __launch_bounds__(256) void prep_fused(
    const float* __restrict__ X, _Float16* __restrict__ Xh, _Float16* __restrict__ Xt)
{
    __shared__ float tl[64][68];
    const int b = blockIdx.z, c0 = blockIdx.y * 64, n0 = blockIdx.x * 64;
    const int t = threadIdx.x;
    const int r0 = t >> 4;
    const int q = (t & 15) * 4;
    const float* Xb = X + ((long)b * 256 + c0) * 4096 + n0;
    _Float16* Xhb = Xh + ((long)b * 256 + c0) * 4096 + n0;
    #pragma unroll
    for (int i = 0; i < 4; ++i) {
        const int r = r0 + i * 16;
        const float4 v = *(const float4*)(Xb + (long)r * 4096 + q);
        tl[r][q + 0] = v.x; tl[r][q + 1] = v.y;
        tl[r][q + 2] = v.z; tl[r][q + 3] = v.w;
        half4 h = { (_Float16)v.x, (_Float16)v.y, (_Float16)v.z, (_Float16)v.w };
        *(half4*)(Xhb + (long)r * 4096 + q) = h;
    }
    __syncthreads();
    const int nn = t >> 2, cc = (t & 3) * 16;
    _Float16* Xtb = Xt + ((long)b * 4096 + n0 + nn) * 256 + c0 + cc;
    half8 o0, o1;
    #pragma unroll
    for (int k = 0; k < 8; ++k) o0[k] = (_Float16)tl[cc + k][nn];
    #pragma unroll
    for (int k = 0; k < 8; ++k) o1[k] = (_Float16)tl[cc + 8 + k][nn];
    *(half8*)(Xtb) = o0;
    *(half8*)(Xtb + 8) = o1;
}

// ---------------------------------------------------------------------------
// Gram split-K: pG[s][b] = Xh_b[:, s*512:(s+1)*512] . (same)^T
// pG lives in d_out. Slab stride 1048576 floats.
// T1 XCD swizzle: 512 blocks (%8==0), bijective remap so the 4 (m,n)-tiles of
// each (b,s) run on ONE XCD -> shared 128KB row-slabs become L2-local.
// ---------------------------------------------------------------------------
__global__ __launch_bounds__(256) void gram_split(const _Float16* __restrict__ Xh,
                                                  float* __restrict__ pG)
{
    __shared__ _Float16 Al[128 * 32];
    __shared__ _Float16 Bl[128 * 32];
    // bijective swizzle: grid (2,2,128) = 512 blocks
    const int hw = blockIdx.x + 2 * blockIdx.y + 4 * blockIdx.z;
    const int f  = (hw & 7) * 64 + (hw >> 3);
    const int bx = f & 1, by = (f >> 1) & 1, bz = f >> 2;
    const int b = bz >> 3, s = bz & 7;
    const int m0 = by * 128, n0 = bx * 128;
    const _Float16* Xb = Xh + (long)b * 256 * 4096;
    const int t = threadIdx.x, lane = t & 63, wv = t >> 6;
    const int wm = (wv >> 1) * 64, wn = (wv & 1) * 64;
    f32x4 acc[4][4] = {};

    const int kbeg = s * 512, kend = kbeg + 512;
    for (int k0 = kbeg; k0 < kend; k0 += 32) {
        __syncthreads();
        #pragma unroll
        for (int r = 0; r < 2; ++r) {
            const int e = (r * 256 + t) * 8;
            const int row = e >> 5, col = e & 31;
            GLOAD_LDS16(Xb + (long)(m0 + row) * 4096 + k0 + col, &Al[e]);
            GLOAD_LDS16(Xb + (long)(n0 + row) * 4096 + k0 + col, &Bl[e]);
        }
        __syncthreads();
        half8 af[4], bf[4];
        #pragma unroll
        for (int ff = 0; ff < 4; ++ff) {
            af[ff] = *(const half8*)&Al[(wm + ff * 16 + (lane & 15)) * 32 + (lane >> 4) * 8];
            bf[ff] = *(const half8*)&Bl[(wn + ff * 16 + (lane & 15)) * 32 + (lane >> 4) * 8];
        }
        #pragma unroll
        for (int i = 0; i < 4; ++i)
            #pragma unroll
            for (int j = 0; j < 4; ++j)
                acc[i][j] = __builtin_amdgcn_mfma_f32_16x16x32_f16(af[i], bf[j], acc[i][j], 0, 0, 0);
    }
    float* pGb = pG + (long)s * 1048576 + (long)b * 65536;
    #pragma unroll
    for (int i = 0; i < 4; ++i)
        #pragma unroll
        for (int j = 0; j < 4; ++j) {
            const int row = m0 + wm + i * 16 + (lane >> 4) * 4;
            const int col = n0 + wn + j * 16 + (lane & 15);
            float* gp = pGb + (long)row * 256 + col;
            #pragma unroll
            for (int r = 0; r < 4; ++r) gp[(long)r * 256] = acc[i][j][r];
        }
}

// ---------------------------------------------------------------------------
// G = sum_s pG[s]  (fixed order -> deterministic)
// ---------------------------------------------------------------------------
__global__ __launch_bounds__(256) void reduce_g(const float* __restrict__ pG,
                                                float* __restrict__ G)
{
    const long i = ((long)blockIdx.x * 256 + threadIdx.x) * 4;
    f32x4 s = {};
    #pragma unroll
    for (int k = 0; k < 8; ++k) {
        const float4 v = *(const float4*)(pG + (long)k * 1048576 + i);
        s[0] += v.x; s[1] += v.y; s[2] += v.z; s[3] += v.w;
    }
    *(f32x4*)(G + i) = s;
}

// ---------------------------------------------------------------------------
// snorm: Qn[b][r] = T[b][r] . wqkv[r]  for r in [0,512)  (q/k norms^2).
// ---------------------------------------------------------------------------
__global__ __launch_bounds__(256) void snorm_kernel(
    const float* __restrict__ T, const float* __restrict__ wqkv,
    float* __restrict__ Qn)
{
    const int gw = (int)((blockIdx.x * 256 + threadIdx.x) >> 6);
    const int lane = threadIdx.x & 63;
    const int b = gw >> 9, r = gw & 511;
    const float4 a = *(const float4*)(T + (long)b * 131072 + (long)r * 256 + lane * 4);
    const float4 w = *(const float4*)(wqkv + (long)r * 256 + lane * 4);
    float s = a.x * w.x + a.y * w.y + a.z * w.z + a.w * w.w;
    #pragma unroll
    for (int off = 32; off; off >>= 1) s += __shfl_xor(s, off, 64);
    if (lane == 0) Qn[(long)b * 512 + r] = s;
}

// ---------------------------------------------------------------------------
// attn2: per (b,h): softmax(S1 head-block / (qn kn) * temp) @ Wv_h -> M rows.
// S1 and Mout alias (tile staged to LDS first; blocks touch disjoint rows).
// ---------------------------------------------------------------------------
__global__ __launch_bounds__(256) void attn2_kernel(
    const float* __restrict__ S1, const float* __restrict__ Qn,
    const float* __restrict__ wqkv, const float* __restrict__ temp,
    float* __restrict__ Mout)
{
    const int bh = blockIdx.x;
    const int b = bh >> 3, h = bh & 7;
    const int t = threadIdx.x;
    __shared__ float pa[32][36];
    __shared__ float qn[32], kn[32];

    {
        const int r = t >> 3, c4 = (t & 7) * 4;
        const float4 v = *(const float4*)(
            S1 + (long)b * 65536 + (long)(h * 32 + r) * 256 + h * 32 + c4);
        pa[r][c4 + 0] = v.x; pa[r][c4 + 1] = v.y;
        pa[r][c4 + 2] = v.z; pa[r][c4 + 3] = v.w;
    }
    if (t < 32)
        qn[t] = fmaxf(sqrtf(Qn[(long)b * 512 + h * 32 + t]), 1e-12f);
    else if (t < 64)
        kn[t - 32] = fmaxf(sqrtf(Qn[(long)b * 512 + 256 + h * 32 + (t - 32)]), 1e-12f);
    __syncthreads();

    if (t < 32) {
        const float qin = temp[h] / qn[t];
        float lg[32];
        float mx = -1e30f;
        #pragma unroll
        for (int d = 0; d < 32; ++d) {
            const float l = pa[t][d] * qin / kn[d];
            lg[d] = l;
            mx = fmaxf(mx, l);
        }
        float s = 0.f;
        #pragma unroll
        for (int d = 0; d < 32; ++d) { lg[d] = __expf(lg[d] - mx); s += lg[d]; }
        const float inv = 1.0f / s;
        #pragma unroll
        for (int d = 0; d < 32; ++d) pa[t][d] = lg[d] * inv;
    }
    __syncthreads();

    float accm[32];
    #pragma unroll
    for (int c = 0; c < 32; ++c) accm[c] = 0.f;
    const float* wvp = wqkv + (long)(512 + h * 32) * 256 + t;
    #pragma unroll 4
    for (int d = 0; d < 32; ++d) {
        const float wvv = wvp[(long)d * 256];
        #pragma unroll
        for (int c = 0; c < 32; ++c) accm[c] += pa[c][d] * wvv;
    }
    float* mo = Mout + (long)b * 65536 + (long)(h * 32) * 256 + t;
    #pragma unroll
    for (int c = 0; c < 32; ++c) mo[(long)c * 256] = accm[c];
}

// ---------------------------------------------------------------------------
// out_fused (R6-validated structure, 158.6us total): dbuf K-loop, S2 gate
// fused as 5th A-fragment, LDS-staged coalesced epilogue.
// + T1 XCD swizzle (1024 blocks %8==0): consecutive remapped blocks share one
// batch's Ph/Xt/Xh slabs -> per-XCD L2 (4MB) holds them.
// ---------------------------------------------------------------------------
__global__ __launch_bounds__(256) void out_fused(
    const _Float16* __restrict__ Ph, const _Float16* __restrict__ Xt,
    const _Float16* __restrict__ Xh, const _Float16* __restrict__ W2h,
    float* __restrict__ out)
{
    __shared__ __align__(16) char smem[64 * 132 * 4];   // 33792B: [buf0 16K][buf1 16K]
    __shared__ float S2l[16][132];
    float (*cst)[132] = (float(*)[132])smem;

    // bijective swizzle: grid (32,2,16) = 1024 blocks
    const int hw = blockIdx.x + 32 * blockIdx.y + 64 * blockIdx.z;
    const int f  = (hw & 7) * 128 + (hw >> 3);
    const int bx = f & 31, by = (f >> 5) & 1, bz = f >> 6;

    const int b = bz;
    const int m0 = by * 128, n0 = bx * 128;
    const _Float16* Ab = Ph + (long)b * 65536;
    const _Float16* Bb = Xt + (long)b * 1048576;
    const _Float16* W2b = W2h + (long)b * 4096;
    const int t = threadIdx.x, lane = t & 63, wv = t >> 6;
    const int wm = (wv >> 1) * 64, wn = (wv & 1) * 64;

    f32x4 acc[4][4] = {};
    f32x4 s2acc[4] = {};

#define OF_STAGE(P, K0) do {                                                     \
        _Float16* Al_ = (_Float16*)(smem + (P) * 16384);                         \
        _Float16* Bl_ = (_Float16*)(smem + (P) * 16384 + 8192);                  \
        _Pragma("unroll")                                                        \
        for (int r_ = 0; r_ < 2; ++r_) {                                         \
            const int e_ = (r_ * 256 + t) * 8;                                   \
            const int row_ = e_ >> 5, col_ = e_ & 31;                            \
            GLOAD_LDS16(Ab + (long)(m0 + row_) * 256 + (K0) + col_, &Al_[e_]);   \
            GLOAD_LDS16(Bb + (long)(n0 + row_) * 256 + (K0) + col_, &Bl_[e_]);   \
        } } while (0)

    OF_STAGE(0, 0);
    __syncthreads();                    // first tile landed (vmcnt(0) drain)
    int cur = 0;
    for (int ks = 0; ks < 8; ++ks) {
        if (ks < 7) OF_STAGE(cur ^ 1, (ks + 1) * 32);   // overlap with MFMA below
        const int k0 = ks * 32;
        const half8 wf = *(const half8*)(W2b + (long)(lane & 15) * 256 + k0 + (lane >> 4) * 8);
        const _Float16* Al = (const _Float16*)(smem + cur * 16384);
        const _Float16* Bl = (const _Float16*)(smem + cur * 16384 + 8192);
        half8 af[4], bf[4];
        #pragma unroll
        for (int ff = 0; ff < 4; ++ff) {
            af[ff] = *(const half8*)&Al[(wm + ff * 16 + (lane & 15)) * 32 + (lane >> 4) * 8];
            bf[ff] = *(const half8*)&Bl[(wn + ff * 16 + (lane & 15)) * 32 + (lane >> 4) * 8];
        }
        #pragma unroll
        for (int i = 0; i < 4; ++i)
            #pragma unroll
            for (int j = 0; j < 4; ++j)
                acc[i][j] = __builtin_amdgcn_mfma_f32_16x16x32_f16(af[i], bf[j], acc[i][j], 0, 0, 0);
        #pragma unroll
        for (int j = 0; j < 4; ++j)
            s2acc[j] = __builtin_amdgcn_mfma_f32_16x16x32_f16(wf, bf[j], s2acc[j], 0, 0, 0);
        __syncthreads();                // drains vmcnt(0): next tile landed
        cur ^= 1;
    }
#undef OF_STAGE

    // smem free (all reads done at final barrier); becomes cst
    if (wm == 0) {
        #pragma unroll
        for (int j = 0; j < 4; ++j)
            #pragma unroll
            for (int r = 0; r < 4; ++r)
                S2l[(lane >> 4) * 4 + r][wn + j * 16 + (lane & 15)] = s2acc[j][r];
    }

    const _Float16* Xhb = Xh + (long)b * 1048576;
    float* ob = out + (long)b * 1048576;

    #pragma unroll
    for (int hf = 0; hf < 2; ++hf) {
        if (wm == hf * 64) {
            #pragma unroll
            for (int i = 0; i < 4; ++i)
                #pragma unroll
                for (int j = 0; j < 4; ++j)
                    #pragma unroll
                    for (int r = 0; r < 4; ++r)
                        cst[i * 16 + (lane >> 4) * 4 + r][wn + j * 16 + (lane & 15)] = acc[i][j][r];
        }
        __syncthreads();
        #pragma unroll
        for (int it = 0; it < 8; ++it) {
            const int row = it * 8 + (t >> 5);
            const int col = (t & 31) * 4;
            const int c = m0 + hf * 64 + row;
            const float4 v = *(const float4*)&cst[row][col];
            const float4 s2 = *(const float4*)&S2l[c >> 4][col];
            const half4 xv = *(const half4*)(Xhb + (long)c * 4096 + n0 + col);
            float4 o;
            o.x = (float)xv[0] * sigmoidf_(s2.x) + v.x;
            o.y = (float)xv[1] * sigmoidf_(s2.y) + v.y;
            o.z = (float)xv[2] * sigmoidf_(s2.z) + v.z;
            o.w = (float)xv[3] * sigmoidf_(s2.w) + v.w;
            *(float4*)(ob + (long)c * 4096 + n0 + col) = o;
        }
        __syncthreads();
    }
}

// ---------------------------------------------------------------------------
// Generic 64x64-tile fp32 GEMM. DIAG: n0=m0. HC: also write f16 copy of C.
// SWZ: bijective XCD block remap (requires grid total %8==0).
// ---------------------------------------------------------------------------
template <bool BT, bool EPI, bool DIAG, bool HC, bool SWZ>
__global__ __launch_bounds__(256) void gemm64(
    const float* __restrict__ A, const float* __restrict__ B, float* __restrict__ C,
    int M, int N, int K, long sA, long sB, long sC,
    const float* __restrict__ X, const float* __restrict__ WP,
    _Float16* __restrict__ Hc)
{
    __shared__ float As[32][68];
    __shared__ float Bs[32][68];
    int bx = blockIdx.x, by = blockIdx.y, bz = blockIdx.z;
    if (SWZ) {
        const int nx = gridDim.x, ny = gridDim.y;
        const int tot = nx * ny * gridDim.z;
        const int hw = bx + nx * (by + ny * bz);
        const int f = (hw & 7) * (tot >> 3) + (hw >> 3);
        bx = f % nx; by = (f / nx) % ny; bz = f / (nx * ny);
    }
    const int b = bz;
    const float* Ab = A + (long)b * sA;
    const float* Bb = B + (long)b * sB;
    float* Cb = C + (long)b * sC;
    const int t = threadIdx.x;
    const int tx = t & 15, ty = t >> 4;
    const int m0 = by * 64;
    const int n0 = DIAG ? m0 : bx * 64;

    float acc[4][4] = {};

    for (int k0 = 0; k0 < K; k0 += 32) {
        __syncthreads();
        #pragma unroll
        for (int f0 = 0; f0 < 512; f0 += 256) {
            const int f1 = f0 + t;
            const int row = f1 >> 3, c4 = f1 & 7;
            const float4 v = *(const float4*)(Ab + (long)(m0 + row) * K + k0 + c4 * 4);
            As[c4 * 4 + 0][row] = v.x;
            As[c4 * 4 + 1][row] = v.y;
            As[c4 * 4 + 2][row] = v.z;
            As[c4 * 4 + 3][row] = v.w;
        }
        if (BT) {
            #pragma unroll
            for (int f0 = 0; f0 < 512; f0 += 256) {
                const int f1 = f0 + t;
                const int row = f1 >> 3, c4 = f1 & 7;
                const float4 v = *(const float4*)(Bb + (long)(n0 + row) * K + k0 + c4 * 4);
                Bs[c4 * 4 + 0][row] = v.x;
                Bs[c4 * 4 + 1][row] = v.y;
                Bs[c4 * 4 + 2][row] = v.z;
                Bs[c4 * 4 + 3][row] = v.w;
            }
        } else {
            #pragma unroll
            for (int f0 = 0; f0 < 512; f0 += 256) {
                const int f1 = f0 + t;
                const int kk = f1 >> 4, c4 = f1 & 15;
                *(float4*)&Bs[kk][c4 * 4] =
                    *(const float4*)(Bb + (long)(k0 + kk) * N + n0 + c4 * 4);
            }
        }
        __syncthreads();
        #pragma unroll
        for (int kk = 0; kk < 32; ++kk) {
            const float4 av = *(const float4*)&As[kk][ty * 4];
            const float4 bv = *(const float4*)&Bs[kk][tx * 4];
            const float a0 = av.x, a1 = av.y, a2 = av.z, a3 = av.w;
            const float b0 = bv.x, b1 = bv.y, b2 = bv.z, b3 = bv.w;
            acc[0][0] += a0 * b0; acc[0][1] += a0 * b1; acc[0][2] += a0 * b2; acc[0][3] += a0 * b3;
            acc[1][0] += a1 * b0; acc[1][1] += a1 * b1; acc[1][2] += a1 * b2; acc[1][3] += a1 * b3;
            acc[2][0] += a2 * b0; acc[2][1] += a2 * b1; acc[2][2] += a2 * b2; acc[2][3] += a2 * b3;
            acc[3][0] += a3 * b0; acc[3][1] += a3 * b1; acc[3][2] += a3 * b2; acc[3][3] += a3 * b3;
        }
    }

    if (EPI) {
        #pragma unroll
        for (int i = 0; i < 4; ++i) {
            const int c = m0 + ty * 4 + i;
            const long nidx = n0 + tx * 4;
            const float4 xv = *(const float4*)(X + ((long)b * 256 + c) * 4096 + nidx);
            const float4 wv = *(const float4*)(WP + ((long)b * 16 + (c >> 4)) * 4096 + nidx);
            float4 o;
            o.x = xv.x * sigmoidf_(wv.x) + acc[i][0];
            o.y = xv.y * sigmoidf_(wv.y) + acc[i][1];
            o.z = xv.z * sigmoidf_(wv.z) + acc[i][2];
            o.w = xv.w * sigmoidf_(wv.w) + acc[i][3];
            *(float4*)(Cb + (long)c * N + nidx) = o;
        }
    } else {
        #pragma unroll
        for (int i = 0; i < 4; ++i) {
            const float4 o = make_float4(acc[i][0], acc[i][1], acc[i][2], acc[i][3]);
            *(float4*)(Cb + (long)(m0 + ty * 4 + i) * N + n0 + tx * 4) = o;
            if (HC) {
                half4 h = { (_Float16)o.x, (_Float16)o.y, (_Float16)o.z, (_Float16)o.w };
                *(half4*)(Hc + (long)b * sC + (long)(m0 + ty * 4 + i) * N + n0 + tx * 4) = h;
            }
        }
    }
}

// ---------------------------------------------------------------------------
// Per-(b,h) attention in Gram space (fallback path only).
// ---------------------------------------------------------------------------
__global__ __launch_bounds__(256) void attn_kernel(
    const float* __restrict__ T, const float* __restrict__ wqkv,
    const float* __restrict__ temp, float* __restrict__ Mout, long tStride)
{
    const int bh = blockIdx.x;
    const int b = bh >> 3, h = bh & 7;
    const int t = threadIdx.x;
    __shared__ float Tq[32][260];
    __shared__ float qk[32][33];
    __shared__ float qn[32], kn[32];
    const float* Tb = T + (long)b * tStride;

    for (int f = t; f < 32 * 64; f += 256) {
        const int r = f >> 6, c4 = f & 63;
        *(float4*)&Tq[r][c4 * 4] = *(const float4*)(Tb + (long)(h * 32 + r) * 256 + c4 * 4);
    }
    __syncthreads();

    if (t < 32) {
        float s = 0.f;
        const float* wq = wqkv + (long)(h * 32 + t) * 256;
        #pragma unroll 4
        for (int k = 0; k < 256; k += 4) {
            const float4 a = *(const float4*)&Tq[t][k];
            const float4 w = *(const float4*)(wq + k);
            s += a.x * w.x + a.y * w.y + a.z * w.z + a.w * w.w;
        }
        qn[t] = fmaxf(sqrtf(s), 1e-12f);
    } else if (t < 64) {
        const int d = t - 32;
        float s = 0.f;
        const float* tk = Tb + (long)(256 + h * 32 + d) * 256;
        const float* wk = wqkv + (long)(256 + h * 32 + d) * 256;
        #pragma unroll 4
        for (int k = 0; k < 256; k += 4) {
            const float4 a = *(const float4*)(tk + k);
            const float4 w = *(const float4*)(wk + k);
            s += a.x * w.x + a.y * w.y + a.z * w.z + a.w * w.w;
        }
        kn[d] = fmaxf(sqrtf(s), 1e-12f);
    }

    {
        const int c = t >> 3, d0 = (t & 7) * 4;
        float s0 = 0, s1 = 0, s2 = 0, s3 = 0;
        const float* wk0 = wqkv + (long)(256 + h * 32 + d0) * 256;
        #pragma unroll 4
        for (int k = 0; k < 256; k += 4) {
            const float4 a = *(const float4*)&Tq[c][k];
            const float4 w0 = *(const float4*)(wk0 + k);
            const float4 w1 = *(const float4*)(wk0 + 256 + k);
            const float4 w2 = *(const float4*)(wk0 + 512 + k);
            const float4 w3 = *(const float4*)(wk0 + 768 + k);
            s0 += a.x * w0.x + a.y * w0.y + a.z * w0.z + a.w * w0.w;
            s1 += a.x * w1.x + a.y * w1.y + a.z * w1.z + a.w * w1.w;
            s2 += a.x * w2.x + a.y * w2.y + a.z * w2.z + a.w * w2.w;
            s3 += a.x * w3.x + a.y * w3.y + a.z * w3.z + a.w * w3.w;
        }
        qk[c][d0 + 0] = s0;
        qk[c][d0 + 1] = s1;
        qk[c][d0 + 2] = s2;
        qk[c][d0 + 3] = s3;
    }
    __syncthreads();

    if (t < 32) {
        const float tscale = temp[h];
        const float qin = tscale / qn[t];
        float lg[32];
        float mx = -1e30f;
        #pragma unroll
        for (int d = 0; d < 32; ++d) {
            const float l = qk[t][d] * qin / kn[d];
            lg[d] = l;
            mx = fmaxf(mx, l);
        }
        float s = 0.f;
        #pragma unroll
        for (int d = 0; d < 32; ++d) { lg[d] = __expf(lg[d] - mx); s += lg[d]; }
        const float inv = 1.0f / s;
        #pragma unroll
        for (int d = 0; d < 32; ++d) qk[t][d] = lg[d] * inv;
    }
    __syncthreads();

    float accm[32];
    #pragma unroll
    for (int c = 0; c < 32; ++c) accm[c] = 0.f;
    const float* wvp = wqkv + (long)(512 + h * 32) * 256 + t;
    #pragma unroll 4
    for (int d = 0; d < 32; ++d) {
        const float wvv = wvp[(long)d * 256];
        #pragma unroll
        for (int c = 0; c < 32; ++c) accm[c] += qk[c][d] * wvv;
    }
    float* mo = Mout + (long)b * 256 * 256 + (long)(h * 32) * 256 + t;
    #pragma unroll
    for (int c = 0; c < 32; ++c) mo[(long)c * 256] = accm[c];
}

// ---------------------------------------------------------------------------
// W2[b][g][i] = (softmax(gn_b) . P[b][16g:16g+16][i])
// ---------------------------------------------------------------------------
template <typename OT>
__global__ __launch_bounds__(256) void w2_kernel(
    const float* __restrict__ P, const float* __restrict__ gnb, OT* __restrict__ W2)
{
    const int b = blockIdx.x, i = threadIdx.x;
    float e[16];
    float mx = -1e30f;
    #pragma unroll
    for (int c = 0; c < 16; ++c) mx = fmaxf(mx, gnb[c]);
    float s = 0.f;
    #pragma unroll
    for (int c = 0; c < 16; ++c) { e[c] = __expf(gnb[c] - mx); s += e[c]; }
    const float inv = 1.0f / s;
    const float* Pb = P + (long)b * 256 * 256 + i;
    #pragma unroll
    for (int g = 0; g < 16; ++g) {
        float acc = 0.f;
        #pragma unroll
        for (int c = 0; c < 16; ++c) acc += e[c] * Pb[(long)(g * 16 + c) * 256];
        W2[((long)b * 16 + g) * 256 + i] = (OT)(acc * inv);
    }
}

// ---------------------------------------------------------------------------
// WP[b][g][n] = W2_b[g] . X_b[:,n]  (fallback path only)
// ---------------------------------------------------------------------------
__global__ __launch_bounds__(256) void wpre_kernel(
    const float* __restrict__ W2, const float* __restrict__ X, float* __restrict__ WP)
{
    __shared__ float w2s[16][260];
    const int b = blockIdx.y;
    const int n = blockIdx.x * 256 + threadIdx.x;
    for (int f = threadIdx.x; f < 16 * 64; f += 256) {
        const int g = f >> 6, c4 = f & 63;
        *(float4*)&w2s[g][c4 * 4] = *(const float4*)(W2 + ((long)b * 16 + g) * 256 + c4 * 4);
    }
    __syncthreads();
    float acc[16] = {};
    const float* xb = X + (long)b * 256 * 4096 + n;
    for (int k = 0; k < 256; ++k) {
        const float xv = xb[(long)k * 4096];
        #pragma unroll
        for (int g = 0; g < 16; ++g) acc[g] += w2s[g][k] * xv;
    }
    #pragma unroll
    for (int g = 0; g < 16; ++g) WP[((long)b * 16 + g) * 4096 + n] = acc[g];
}

// ---------------------------------------------------------------------------
extern "C" void kernel_launch(void* const* d_in, const int* in_sizes, int n_in,
                              void* d_out, int out_size, void* d_ws, size_t ws_size,
                              hipStream_t stream)
{
    const float* x     = (const float*)d_in[0];
    const float* gnb   = (const float*)d_in[4];
    const float* wqkv  = (const float*)d_in[5];
    const float* wproj = (const float*)d_in[6];
    const float* temp  = (const float*)d_in[7];
    float* out = (float*)d_out;

    if (ws_size >= 82051072ULL) {
        // Workspace: [Xh 32M][Xt 32M][G/S1/Mm 4M][pool: T(8M)+Qn(32K) -> {P,Ph,W2h}]
        // Gram split-K partials (32 MB) live in d_out (dead until out_fused).
        char* w = (char*)d_ws;
        _Float16* Xh = (_Float16*)w;
        _Float16* Xt = (_Float16*)(w + 33554432);
        float*    G  = (float*)(w + 67108864);
        float*    S1 = G;                           // overlay: G dead after T-gemm
        float*    Mm = G;                           // overlay: attn2 stages S1 in LDS
        char*     pool = w + 71303168;
        float*    T  = (float*)pool;                // 512x256x16 fp32 = 8MB
        float*    Qn = (float*)(pool + 8388608);    // 32KB norms^2
        float*    P  = (float*)pool;                // overwrites dead T
        _Float16* Ph = (_Float16*)(pool + 4194304);
        _Float16* W2h = (_Float16*)(pool + 4194304 + 2097152);
        float*    pG = (float*)d_out;               // scratch: fully overwritten later

        // 1. X -> Xh + Xt (one pass)
        prep_fused<<<dim3(64, 4, 16), 256, 0, stream>>>(x, Xh, Xt);
        // 2. Gram split-K partials into d_out (XCD-swizzled)
        gram_split<<<dim3(2, 2, 128), 256, 0, stream>>>(Xh, pG);
        // 3. G = sum of 8 partials (fixed order)
        reduce_g<<<1024, 256, 0, stream>>>(pG, G);
        // 4. T = wqkv[0:512] @ G_b  (XCD-swizzled)
        gemm64<false, false, false, false, true><<<dim3(4, 8, 16), 256, 0, stream>>>(
            wqkv, G, T, 512, 256, 256, 0L, 65536L, 131072L,
            nullptr, nullptr, nullptr);
        // 5. Qn[b][r] = T[b][r].wqkv[r]
        snorm_kernel<<<2048, 256, 0, stream>>>(T, wqkv, Qn);
        // 6. S1 diag head-blocks = Tq @ Wk^T (64 blocks, no swizzle)
        gemm64<true, false, true, false, false><<<dim3(1, 4, 16), 256, 0, stream>>>(
            T, wqkv + 65536, S1, 256, 256, 256, 131072L, 0L, 65536L,
            nullptr, nullptr, nullptr);
        // 7. softmax + @Wv -> Mm (aliases S1, LDS-staged)
        attn2_kernel<<<128, 256, 0, stream>>>(S1, Qn, wqkv, temp, Mm);
        // 8. P = wproj @ Mm (fp32) + f16 copy Ph (fused cvt, XCD-swizzled)
        gemm64<false, false, false, true, true><<<dim3(4, 4, 16), 256, 0, stream>>>(
            wproj, Mm, P, 256, 256, 256, 0L, 65536L, 65536L,
            nullptr, nullptr, Ph);
        // 9. W2h = softmax(gn_b)-weighted group sums of P rows (f16)
        w2_kernel<_Float16><<<16, 256, 0, stream>>>(P, gnb, W2h);
        // 10. out = Ph@X + Xh*sigmoid(W2h@X)  (dbuf + fused S2, XCD-swizzled)
        out_fused<<<dim3(32, 2, 16), 256, 0, stream>>>(Ph, Xt, Xh, W2h, out);
    } else {
        // Fallback: fp32 path (~30 MB workspace)
        float* ws = (float*)d_ws;
        float* G  = ws;
        float* T  = G  + 16L * 65536;
        float* Mm = T  + 16L * 196608;
        float* P  = Mm + 16L * 65536;
        float* W2 = P  + 16L * 65536;
        float* WP = W2 + 16L * 4096;

        gemm64<true, false, false, false, false><<<dim3(4, 4, 16), 256, 0, stream>>>(
            x, x, G, 256, 256, 4096, 1048576L, 1048576L, 65536L, nullptr, nullptr, nullptr);
        gemm64<false, false, false, false, false><<<dim3(4, 12, 16), 256, 0, stream>>>(
            wqkv, G, T, 768, 256, 256, 0L, 65536L, 196608L, nullptr, nullptr, nullptr);
        attn_kernel<<<128, 256, 0, stream>>>(T, wqkv, temp, Mm, 196608L);
        gemm64<false, false, false, false, false><<<dim3(4, 4, 16), 256, 0, stream>>>(
            wproj, Mm, P, 256, 256, 256, 0L, 65536L, 65536L, nullptr, nullptr, nullptr);
        w2_kernel<float><<<16, 256, 0, stream>>>(P, gnb, W2);
        wpre_kernel<<<dim3(16, 16), 256, 0, stream>>>(W2, x, WP);
        gemm64<false, true, false, false, false><<<dim3(64, 4, 16), 256, 0, stream>>>(
            P, x, out, 256, 4096, 256, 65536L, 1048576L, 1048576L, x, WP, nullptr);
    }
}